// Round 8
// baseline (762.249 us; speedup 1.0000x reference)
//
#include <hip/hip_runtime.h>

#define N_NODES 100000
#define N_EDGES 1600000
#define DIM 64
#define NLAYER 4
#define NGRAPH 128
#define BN_EPS 1e-5f
#define NSHARD 16

typedef unsigned short ushort_t;
typedef unsigned int uint_t;

__device__ __forceinline__ ushort_t f2bf(float f) {
    uint_t u = __float_as_uint(f);
    uint_t r = (u + 0x7FFFu + ((u >> 16) & 1u)) >> 16;
    return (ushort_t)r;
}
__device__ __forceinline__ float bf2f(uint_t u) {
    return __uint_as_float(u << 16);
}
__device__ __forceinline__ void bf8_to_f32(const uint4 v, float f[8]) {
    f[0] = __uint_as_float(v.x << 16);
    f[1] = __uint_as_float(v.x & 0xFFFF0000u);
    f[2] = __uint_as_float(v.y << 16);
    f[3] = __uint_as_float(v.y & 0xFFFF0000u);
    f[4] = __uint_as_float(v.z << 16);
    f[5] = __uint_as_float(v.z & 0xFFFF0000u);
    f[6] = __uint_as_float(v.w << 16);
    f[7] = __uint_as_float(v.w & 0xFFFF0000u);
}

// ---------------- CSR build (unchanged from r7) ----------------

__global__ void k_hist(const int* __restrict__ ei, int* __restrict__ cntS,
                       int* __restrict__ rank) {
    int e = blockIdx.x * blockDim.x + threadIdx.x;
    if (e < N_EDGES) {
        int d = ei[N_EDGES + e];
        int s = blockIdx.x & (NSHARD - 1);
        rank[e] = atomicAdd(&cntS[s * N_NODES + d], 1);
    }
}

__global__ void k_sumsh(int* __restrict__ cntS, int* __restrict__ cnt) {
    int i = blockIdx.x * blockDim.x + threadIdx.x;
    if (i < N_NODES) {
        int run = 0;
#pragma unroll
        for (int s = 0; s < NSHARD; s++) {
            int c = cntS[s * N_NODES + i];
            cntS[s * N_NODES + i] = run;
            run += c;
        }
        cnt[i] = run;
    }
}

__global__ void k_scan1(const int* __restrict__ cnt, int* __restrict__ exc,
                        int* __restrict__ bsums) {
    __shared__ int s[256];
    int i = blockIdx.x * 256 + threadIdx.x;
    int v = (i < N_NODES) ? cnt[i] : 0;
    s[threadIdx.x] = v;
    __syncthreads();
    for (int off = 1; off < 256; off <<= 1) {
        int t = (threadIdx.x >= off) ? s[threadIdx.x - off] : 0;
        __syncthreads();
        s[threadIdx.x] += t;
        __syncthreads();
    }
    if (i < N_NODES) exc[i] = s[threadIdx.x] - v;
    if (threadIdx.x == 255) bsums[blockIdx.x] = s[255];
}

__global__ void k_scan2(const int* __restrict__ bsums, int* __restrict__ boffs, int nb) {
    __shared__ int s[512];
    int v = ((int)threadIdx.x < nb) ? bsums[threadIdx.x] : 0;
    s[threadIdx.x] = v;
    __syncthreads();
    for (int off = 1; off < 512; off <<= 1) {
        int t = (threadIdx.x >= off) ? s[threadIdx.x - off] : 0;
        __syncthreads();
        s[threadIdx.x] += t;
        __syncthreads();
    }
    if ((int)threadIdx.x < nb) boffs[threadIdx.x] = s[threadIdx.x] - v;
}

__global__ void k_scan3(int* __restrict__ exc, const int* __restrict__ boffs) {
    int i = blockIdx.x * 256 + threadIdx.x;
    if (i < N_NODES) exc[i] += boffs[blockIdx.x];
}

__global__ void k_fill(const int* __restrict__ ei, const int* __restrict__ rowptr,
                       const int* __restrict__ cntS, const int* __restrict__ rank,
                       int* __restrict__ csr) {
    int e = blockIdx.x * blockDim.x + threadIdx.x;
    if (e < N_EDGES) {
        int d = ei[N_EDGES + e];
        int s = blockIdx.x & (NSHARD - 1);
        csr[rowptr[d] + cntS[s * N_NODES + d] + rank[e]] = ei[e];
    }
}

__global__ void k_prep(const int* __restrict__ cnt, const int* __restrict__ batch,
                       float* __restrict__ invdeg, float* __restrict__ invg) {
    int i = blockIdx.x * blockDim.x + threadIdx.x;
    if (i < N_NODES) invdeg[i] = 1.0f / (float)max(cnt[i], 1);
    if (i < NGRAPH) {
        int key = i, lo = 0, hi = N_NODES;
        while (lo < hi) { int m = (lo + hi) >> 1; if (batch[m] < key) lo = m + 1; else hi = m; }
        int a = lo;
        key = i + 1; lo = 0; hi = N_NODES;
        while (lo < hi) { int m = (lo + hi) >> 1; if (batch[m] < key) lo = m + 1; else hi = m; }
        invg[i] = 1.0f / (float)max(lo - a, 1);
    }
}

__global__ void k_xcast(const float* __restrict__ x, ushort_t* __restrict__ xh) {
    int i = blockIdx.x * blockDim.x + threadIdx.x;
    if (i < N_NODES * 16) {
        const float4 v = ((const float4*)x)[i];
        ushort4 u;
        u.x = f2bf(v.x); u.y = f2bf(v.y); u.z = f2bf(v.z); u.w = f2bf(v.w);
        ((ushort4*)xh)[i] = u;
    }
}

// One masked group of 8 edges; bf16 rows, octet layout (q=lane>>3 edge slot,
// r=lane&7 column octet). 1 idx load + 1 dwordx4 gather per 8 edges.
__device__ __forceinline__ void grp8b(const ushort_t* __restrict__ h,
                                      const int* __restrict__ cp,
                                      int e, int deg, int q, int r,
                                      float acc[8]) {
    const int last = deg - 1;
    const int e0 = e + q;
    int i0 = cp[min(e0, last)];
    float m0 = (e0 < deg) ? 1.f : 0.f;
    const uint4 v = *(const uint4*)(h + (size_t)i0 * 64 + r * 8);
    float f[8];
    bf8_to_f32(v, f);
#pragma unroll
    for (int j = 0; j < 8; j++) acc[j] = fmaf(f[j], m0, acc[j]);
}

// ---------------- k_agg: t = h + mean_nb(h), output FEATURE-MAJOR bf16 --------
// 16-node chunk per wave (6250 waves -> ~6 waves/SIMD for gather latency
// hiding). t staged in wave-private LDS (row stride 66 ushorts -> odd-dword
// stride, conflict-free column reads), then written transposed tT[k][n].

#define AGG_CHUNK 16

__global__ __launch_bounds__(256, 4)
void k_agg(const ushort_t* __restrict__ h, const int* __restrict__ rowptr,
           const int* __restrict__ cnt, const int* __restrict__ csr,
           const float* __restrict__ invdeg, ushort_t* __restrict__ tT) {
    __shared__ ushort_t sm[4][AGG_CHUNK * 66];
    const int w = threadIdx.x >> 6;
    const int lane = threadIdx.x & 63;
    const int q = lane >> 3;
    const int r = lane & 7;
    const int wid = __builtin_amdgcn_readfirstlane((blockIdx.x << 2) | w);
    if (wid >= N_NODES / AGG_CHUNK) return;
    const int n0 = wid * AGG_CHUNK;
    ushort_t* my = sm[w];

    for (int pp = 0; pp < AGG_CHUNK; pp += 2) {
        const int n = n0 + pp;
        const int sa = rowptr[n],     da = cnt[n];
        const int sb = rowptr[n + 1], db = cnt[n + 1];
        const float idga = invdeg[n], idgb = invdeg[n + 1];
        const int* __restrict__ ca = csr + sa;
        const int* __restrict__ cb = csr + sb;

        float aa[8] = {0,0,0,0,0,0,0,0};
        float ab[8] = {0,0,0,0,0,0,0,0};
        const int m = min(da, db);
        int e = 0;
        for (; e < m; e += 8) {
            grp8b(h, ca, e, da, q, r, aa);
            grp8b(h, cb, e, db, q, r, ab);
        }
        for (; e < da; e += 8) grp8b(h, ca, e, da, q, r, aa);
        for (; e < db; e += 8) grp8b(h, cb, e, db, q, r, ab);

#pragma unroll
        for (int j = 0; j < 8; j++) {
            aa[j] += __shfl_xor(aa[j], 8, 64);
            aa[j] += __shfl_xor(aa[j], 16, 64);
            aa[j] += __shfl_xor(aa[j], 32, 64);
            ab[j] += __shfl_xor(ab[j], 8, 64);
            ab[j] += __shfl_xor(ab[j], 16, 64);
            ab[j] += __shfl_xor(ab[j], 32, 64);
        }

        const uint4 sva = *(const uint4*)(h + (size_t)n * 64 + r * 8);
        const uint4 svb = *(const uint4*)(h + (size_t)(n + 1) * 64 + r * 8);
        float sa8[8], sb8[8];
        bf8_to_f32(sva, sa8);
        bf8_to_f32(svb, sb8);
        float ta[8], tb[8];
#pragma unroll
        for (int j = 0; j < 8; j++) {
            ta[j] = fmaf(aa[j], idga, sa8[j]);
            tb[j] = fmaf(ab[j], idgb, sb8[j]);
        }

        // stage: lanes q==0 write node pp, q==1 write node pp+1 (conflict-free)
        if (q < 2) {
            const int row = pp + q;
            uint_t* dst = (uint_t*)&my[row * 66 + r * 8];
#pragma unroll
            for (int j2 = 0; j2 < 4; j2++) {
                float lo = q ? tb[2 * j2] : ta[2 * j2];
                float hi = q ? tb[2 * j2 + 1] : ta[2 * j2 + 1];
                dst[j2] = (uint_t)f2bf(lo) | ((uint_t)f2bf(hi) << 16);
            }
        }
    }

    // transposed write: 4 k-rows per iteration, 16 nodes along lanes
    const int nn = lane & 15;
    const int hi = lane >> 4;  // 0..3
    for (int kk = 0; kk < 64; kk += 4) {
        const int k = kk + hi;
        const uint_t v = *(const uint_t*)&my[nn * 66 + (k & ~1)];
        const uint_t bits = (k & 1) ? (v >> 16) : (v & 0xFFFFu);
        tT[(size_t)k * N_NODES + n0 + nn] = (ushort_t)bits;
    }
}

// ---------------- k_mlp1: zT = tT @ W1 + b1 (transposed, scalar weights) ------
// lane = node; W1 row k is wave-uniform -> SGPR; 64 independent acc chains.

__global__ __launch_bounds__(256, 4)
void k_mlp1(const ushort_t* __restrict__ tT, const float* __restrict__ W1,
            const float* __restrict__ b1, float* __restrict__ zT) {
    const int lane = threadIdx.x & 63;
    const int wid = __builtin_amdgcn_readfirstlane((blockIdx.x << 2) | (threadIdx.x >> 6));
    const int n0 = wid * 64;
    if (n0 >= N_NODES) return;
    const int n = n0 + lane;
    const int nc = min(n, N_NODES - 1);

    float acc[64];
#pragma unroll
    for (int o = 0; o < 64; o++) acc[o] = 0.f;

    for (int k = 0; k < 64; k++) {
        const float tk = bf2f(tT[(size_t)k * N_NODES + nc]);
        const float* __restrict__ Wr = W1 + (k << 6);
#pragma unroll
        for (int o = 0; o < 64; o++) acc[o] = fmaf(tk, Wr[o], acc[o]);
    }
    if (n < N_NODES) {
#pragma unroll
        for (int o = 0; o < 64; o++)
            zT[(size_t)o * N_NODES + n] = acc[o] + b1[o];
    }
}

// ---------------- k_moments: colsum/colsumsq from zT rows (coalesced) ---------

__global__ void k_moments(const float* __restrict__ zT, float* __restrict__ colsum,
                          float* __restrict__ colsumsq) {
    const int row = blockIdx.x >> 3;   // 64 rows x 8 parts
    const int part = blockIdx.x & 7;
    const float4* src = (const float4*)(zT + (size_t)row * N_NODES) + part * 3125;
    float s = 0.f, sq = 0.f;
    for (int i = threadIdx.x; i < 3125; i += 256) {
        const float4 v = src[i];
        s += (v.x + v.y) + (v.z + v.w);
        sq += (v.x * v.x + v.y * v.y) + (v.z * v.z + v.w * v.w);
    }
    __shared__ float rs[256], rq[256];
    rs[threadIdx.x] = s;
    rq[threadIdx.x] = sq;
    __syncthreads();
    for (int off = 128; off > 0; off >>= 1) {
        if ((int)threadIdx.x < off) {
            rs[threadIdx.x] += rs[threadIdx.x + off];
            rq[threadIdx.x] += rq[threadIdx.x + off];
        }
        __syncthreads();
    }
    if (threadIdx.x == 0) {
        atomicAdd(&colsum[row], rs[0]);
        atomicAdd(&colsumsq[row], rq[0]);
    }
}

// ---------------- BN prep ----------------

__global__ void k_bnprep(float* __restrict__ colsum, float* __restrict__ colsumsq,
                         const float* __restrict__ gamma, const float* __restrict__ beta,
                         float* __restrict__ scale, float* __restrict__ shift) {
    int j = threadIdx.x;  // 64 threads
    float invn = 1.0f / (float)N_NODES;
    float mu = colsum[j] * invn;
    float var = colsumsq[j] * invn - mu * mu;
    float rsg = rsqrtf(var + BN_EPS);
    float sc = gamma[j] * rsg;
    scale[j] = sc;
    shift[j] = beta[j] - mu * sc;
    colsum[j] = 0.f;
    colsumsq[j] = 0.f;
}

// ---------------- k_mlp2: h = relu(bn(z))@W2 + b2 (transposed) + pools --------
// GEMV transposed w/ scalar weights; LDS transpose back to node-major for
// hout (bf16 gather rows), node_pool RMW, gacc run-length atomics.

__global__ __launch_bounds__(256, 4)
void k_mlp2(const float* __restrict__ zT, const float* __restrict__ W2,
            const float* __restrict__ b2, const float* __restrict__ scale,
            const float* __restrict__ shift, const int* __restrict__ batch,
            ushort_t* __restrict__ hout, float* __restrict__ node_pool,
            float* __restrict__ gacc, int first) {
    __shared__ ushort_t sm[4][64 * 66];
    const int w = threadIdx.x >> 6;
    const int lane = threadIdx.x & 63;
    const int wid = __builtin_amdgcn_readfirstlane((blockIdx.x << 2) | (threadIdx.x >> 6));
    const int n0 = wid * 64;
    if (n0 >= N_NODES) return;
    const int n = n0 + lane;
    const int nc = min(n, N_NODES - 1);

    float acc[64];
#pragma unroll
    for (int o = 0; o < 64; o++) acc[o] = 0.f;

    for (int k = 0; k < 64; k++) {
        const float zk = zT[(size_t)k * N_NODES + nc];
        const float rv = fmaxf(fmaf(zk, scale[k], shift[k]), 0.f);
        const float* __restrict__ Wr = W2 + (k << 6);
#pragma unroll
        for (int o = 0; o < 64; o++) acc[o] = fmaf(rv, Wr[o], acc[o]);
    }

    // stage own node's h row as bf16 (row stride 66 ushorts, conflict-free)
    uint_t* dst = (uint_t*)&sm[w][lane * 66];
#pragma unroll
    for (int j2 = 0; j2 < 32; j2++) {
        float lo = acc[2 * j2] + b2[2 * j2];
        float hi = acc[2 * j2 + 1] + b2[2 * j2 + 1];
        dst[j2] = (uint_t)f2bf(lo) | ((uint_t)f2bf(hi) << 16);
    }

    const int cntn = min(64, N_NODES - n0);
    int curg = -1;
    float ga = 0.f;
    for (int nn = 0; nn < cntn; nn++) {
        const uint_t v = *(const uint_t*)&sm[w][nn * 66 + (lane & 62)];
        const uint_t bits = (lane & 1) ? (v >> 16) : (v & 0xFFFFu);
        const float hv = __uint_as_float(bits << 16);
        const int node = n0 + nn;
        const size_t off = (size_t)node * 64 + lane;
        if (first) node_pool[off] = hv;
        else node_pool[off] += hv;
        hout[off] = (ushort_t)bits;
        const int g = batch[node];
        if (g != curg) {
            if (curg >= 0) atomicAdd(&gacc[curg * 64 + lane], ga);
            ga = 0.f;
            curg = g;
        }
        ga += hv;
    }
    if (curg >= 0) atomicAdd(&gacc[curg * 64 + lane], ga);
}

__global__ void k_gfinal(const float* __restrict__ gacc, const float* __restrict__ invg,
                         float* __restrict__ gout) {
    int i = blockIdx.x * blockDim.x + threadIdx.x;
    if (i < NGRAPH * 64) gout[i] = gacc[i] * invg[i >> 6];
}

// ---------------- launch ----------------

extern "C" void kernel_launch(void* const* d_in, const int* in_sizes, int n_in,
                              void* d_out, int out_size, void* d_ws, size_t ws_size,
                              hipStream_t stream) {
    (void)in_sizes; (void)n_in; (void)out_size; (void)ws_size;
    const float* x     = (const float*)d_in[0];
    const int*   ei    = (const int*)d_in[1];
    const int*   batch = (const int*)d_in[2];
    const float* W1    = (const float*)d_in[3];
    const float* b1    = (const float*)d_in[4];
    const float* gamma = (const float*)d_in[5];
    const float* beta  = (const float*)d_in[6];
    const float* W2    = (const float*)d_in[7];
    const float* b2    = (const float*)d_in[8];
    float* out = (float*)d_out;  // [N*64] node_pool, then [G*64] g_pool

    // element offsets (4B units)
    size_t o = 0;
    size_t o_cntS    = o; o += (size_t)NSHARD * N_NODES;
    size_t o_colsum  = o; o += 64;
    size_t o_colsq   = o; o += 64;
    size_t o_gacc    = o; o += (size_t)NGRAPH * 64;
    size_t zero_elems = o;
    size_t o_cnt     = o; o += N_NODES;
    size_t o_rowptr  = o; o += N_NODES;
    size_t o_bsums   = o; o += 512;
    size_t o_boffs   = o; o += 512;
    size_t o_invdeg  = o; o += N_NODES;
    size_t o_invg    = o; o += NGRAPH;
    size_t o_scale   = o; o += 64;
    size_t o_shift   = o; o += 64;
    size_t o_csr     = o; o += N_EDGES;
    // rank (1.6M) is dead after k_fill; tT (3.2M elems, bf16 64xN) overlays it
    size_t o_rank    = o;
    size_t o_tT      = o; o += (size_t)64 * N_NODES / 2;   // 3.2M elems >= rank
    size_t o_zT      = o; o += (size_t)64 * N_NODES;       // fp32
    size_t o_hbuf    = o; o += (size_t)N_NODES * 16;       // bf16 [node][feat]
    size_t o_xh      = o; o += (size_t)N_NODES * 16;       // bf16 [node][feat]

    int*   wsi = (int*)d_ws;
    float* wsf = (float*)d_ws;
    int*      cntS   = wsi + o_cntS;
    float*    colsum = wsf + o_colsum;
    float*    colsq  = wsf + o_colsq;
    float*    gacc   = wsf + o_gacc;
    int*      cnt    = wsi + o_cnt;
    int*      rowptr = wsi + o_rowptr;
    int*      bsums  = wsi + o_bsums;
    int*      boffs  = wsi + o_boffs;
    float*    invdeg = wsf + o_invdeg;
    float*    invg   = wsf + o_invg;
    float*    scale  = wsf + o_scale;
    float*    shift  = wsf + o_shift;
    int*      csr    = wsi + o_csr;
    int*      rank   = wsi + o_rank;
    ushort_t* tT     = (ushort_t*)(wsi + o_tT);
    float*    zT     = wsf + o_zT;
    ushort_t* hbuf   = (ushort_t*)(wsi + o_hbuf);
    ushort_t* xh     = (ushort_t*)(wsi + o_xh);

    hipMemsetAsync(d_ws, 0, zero_elems * 4, stream);

    const int eb = (N_EDGES + 255) / 256;
    const int nb = (N_NODES + 255) / 256;  // 391 <= 512

    k_hist<<<eb, 256, 0, stream>>>(ei, cntS, rank);
    k_xcast<<<(N_NODES * 16 + 255) / 256, 256, 0, stream>>>(x, xh);
    k_sumsh<<<nb, 256, 0, stream>>>(cntS, cnt);
    k_scan1<<<nb, 256, 0, stream>>>(cnt, rowptr, bsums);
    k_scan2<<<1, 512, 0, stream>>>(bsums, boffs, nb);
    k_scan3<<<nb, 256, 0, stream>>>(rowptr, boffs);
    k_prep<<<nb, 256, 0, stream>>>(cnt, batch, invdeg, invg);
    k_fill<<<eb, 256, 0, stream>>>(ei, rowptr, cntS, rank, csr);

    const int aggBlocks = (N_NODES / AGG_CHUNK + 3) / 4;       // 1563
    const int mlpBlocks = ((N_NODES + 63) / 64 + 3) / 4;       // 391
    for (int l = 0; l < NLAYER; l++) {
        const ushort_t* h_in = (l == 0) ? xh : hbuf;
        k_agg<<<aggBlocks, 256, 0, stream>>>(h_in, rowptr, cnt, csr, invdeg, tT);
        k_mlp1<<<mlpBlocks, 256, 0, stream>>>(tT, W1 + l * 4096, b1 + l * 64, zT);
        k_moments<<<512, 256, 0, stream>>>(zT, colsum, colsq);
        k_bnprep<<<1, 64, 0, stream>>>(colsum, colsq, gamma + l * 64, beta + l * 64,
                                       scale, shift);
        k_mlp2<<<mlpBlocks, 256, 0, stream>>>(zT, W2 + l * 4096, b2 + l * 64,
                                              scale, shift, batch,
                                              hbuf, out, gacc, (l == 0) ? 1 : 0);
    }
    k_gfinal<<<32, 256, 0, stream>>>(gacc, invg, out + (size_t)N_NODES * 64);
}

// Round 9
// 648.477 us; speedup vs baseline: 1.1754x; 1.1754x over previous
//
#include <hip/hip_runtime.h>

#define N_NODES 100000
#define N_EDGES 1600000
#define DIM 64
#define NLAYER 4
#define NGRAPH 128
#define BN_EPS 1e-5f
#define NSHARD 16
#define AGG_CHUNK 16

typedef unsigned short ushort_t;
typedef unsigned int uint_t;
typedef __attribute__((ext_vector_type(8))) short short8;
typedef __attribute__((ext_vector_type(4))) float f32x4;

__device__ __forceinline__ ushort_t f2bf(float f) {
    uint_t u = __float_as_uint(f);
    uint_t r = (u + 0x7FFFu + ((u >> 16) & 1u)) >> 16;
    return (ushort_t)r;
}
__device__ __forceinline__ void bf8_to_f32(const uint4 v, float f[8]) {
    f[0] = __uint_as_float(v.x << 16);
    f[1] = __uint_as_float(v.x & 0xFFFF0000u);
    f[2] = __uint_as_float(v.y << 16);
    f[3] = __uint_as_float(v.y & 0xFFFF0000u);
    f[4] = __uint_as_float(v.z << 16);
    f[5] = __uint_as_float(v.z & 0xFFFF0000u);
    f[6] = __uint_as_float(v.w << 16);
    f[7] = __uint_as_float(v.w & 0xFFFF0000u);
}

// ---------------- CSR build (r7, unchanged) ----------------

__global__ void k_hist(const int* __restrict__ ei, int* __restrict__ cntS,
                       int* __restrict__ rank) {
    int e = blockIdx.x * blockDim.x + threadIdx.x;
    if (e < N_EDGES) {
        int d = ei[N_EDGES + e];
        int s = blockIdx.x & (NSHARD - 1);
        rank[e] = atomicAdd(&cntS[s * N_NODES + d], 1);
    }
}

__global__ void k_sumsh(int* __restrict__ cntS, int* __restrict__ cnt) {
    int i = blockIdx.x * blockDim.x + threadIdx.x;
    if (i < N_NODES) {
        int run = 0;
#pragma unroll
        for (int s = 0; s < NSHARD; s++) {
            int c = cntS[s * N_NODES + i];
            cntS[s * N_NODES + i] = run;
            run += c;
        }
        cnt[i] = run;
    }
}

__global__ void k_scan1(const int* __restrict__ cnt, int* __restrict__ exc,
                        int* __restrict__ bsums) {
    __shared__ int s[256];
    int i = blockIdx.x * 256 + threadIdx.x;
    int v = (i < N_NODES) ? cnt[i] : 0;
    s[threadIdx.x] = v;
    __syncthreads();
    for (int off = 1; off < 256; off <<= 1) {
        int t = (threadIdx.x >= off) ? s[threadIdx.x - off] : 0;
        __syncthreads();
        s[threadIdx.x] += t;
        __syncthreads();
    }
    if (i < N_NODES) exc[i] = s[threadIdx.x] - v;
    if (threadIdx.x == 255) bsums[blockIdx.x] = s[255];
}

__global__ void k_scan2(const int* __restrict__ bsums, int* __restrict__ boffs, int nb) {
    __shared__ int s[512];
    int v = ((int)threadIdx.x < nb) ? bsums[threadIdx.x] : 0;
    s[threadIdx.x] = v;
    __syncthreads();
    for (int off = 1; off < 512; off <<= 1) {
        int t = (threadIdx.x >= off) ? s[threadIdx.x - off] : 0;
        __syncthreads();
        s[threadIdx.x] += t;
        __syncthreads();
    }
    if ((int)threadIdx.x < nb) boffs[threadIdx.x] = s[threadIdx.x] - v;
}

__global__ void k_scan3(int* __restrict__ exc, const int* __restrict__ boffs) {
    int i = blockIdx.x * 256 + threadIdx.x;
    if (i < N_NODES) exc[i] += boffs[blockIdx.x];
}

__global__ void k_fill(const int* __restrict__ ei, const int* __restrict__ rowptr,
                       const int* __restrict__ cntS, const int* __restrict__ rank,
                       int* __restrict__ csr) {
    int e = blockIdx.x * blockDim.x + threadIdx.x;
    if (e < N_EDGES) {
        int d = ei[N_EDGES + e];
        int s = blockIdx.x & (NSHARD - 1);
        csr[rowptr[d] + cntS[s * N_NODES + d] + rank[e]] = ei[e];
    }
}

__global__ void k_prep(const int* __restrict__ cnt, const int* __restrict__ batch,
                       float* __restrict__ invdeg, float* __restrict__ invg) {
    int i = blockIdx.x * blockDim.x + threadIdx.x;
    if (i < N_NODES) invdeg[i] = 1.0f / (float)max(cnt[i], 1);
    if (i < NGRAPH) {
        int key = i, lo = 0, hi = N_NODES;
        while (lo < hi) { int m = (lo + hi) >> 1; if (batch[m] < key) lo = m + 1; else hi = m; }
        int a = lo;
        key = i + 1; lo = 0; hi = N_NODES;
        while (lo < hi) { int m = (lo + hi) >> 1; if (batch[m] < key) lo = m + 1; else hi = m; }
        invg[i] = 1.0f / (float)max(lo - a, 1);
    }
}

__global__ void k_xcast(const float* __restrict__ x, ushort_t* __restrict__ xh) {
    int i = blockIdx.x * blockDim.x + threadIdx.x;
    if (i < N_NODES * 16) {
        const float4 v = ((const float4*)x)[i];
        ushort4 u;
        u.x = f2bf(v.x); u.y = f2bf(v.y); u.z = f2bf(v.z); u.w = f2bf(v.w);
        ((ushort4*)xh)[i] = u;
    }
}

// One masked group of 8 edges; bf16 rows, octet layout (q=lane>>3 edge slot,
// r=lane&7 column octet). 1 idx load + 1 dwordx4 gather per 8 edges.
__device__ __forceinline__ void grp8b(const ushort_t* __restrict__ h,
                                      const int* __restrict__ cp,
                                      int e, int deg, int q, int r,
                                      float acc[8]) {
    const int last = deg - 1;
    const int e0 = e + q;
    int i0 = cp[min(e0, last)];
    float m0 = (e0 < deg) ? 1.f : 0.f;
    const uint4 v = *(const uint4*)(h + (size_t)i0 * 64 + r * 8);
    float f[8];
    bf8_to_f32(v, f);
#pragma unroll
    for (int j = 0; j < 8; j++) acc[j] = fmaf(f[j], m0, acc[j]);
}

// ---------------- Layer pass A: gather + MFMA GEMV(W1) + BN moments ----------
// Fused. Per wave: gather 16 nodes (r7's octet-bf16 gather), stage t rows
// (bf16) into a wave-private LDS tile, then 8x mfma_f32_16x16x32_bf16 with
// W1 bf16 B-fragments (built once per block in LDS). Replaces the 2048-op
// readlane GEMV per 16 nodes with 8 MFMAs. D layout: col=lane&15 (out),
// row=quad*4+reg (node) [m89]. A layout: m=lane&15, k=quad*8+j [m120].

__global__ __launch_bounds__(256, 4)
void k_passA(const ushort_t* __restrict__ h, const float* __restrict__ W1,
             const float* __restrict__ b1,
             const int* __restrict__ rowptr, const int* __restrict__ cnt,
             const int* __restrict__ csr, const float* __restrict__ invdeg,
             float* __restrict__ z, float* __restrict__ colsum,
             float* __restrict__ colsumsq) {
    __shared__ ushort_t wfrag[512 * 8];     // [(hh*4+c)*64+lane] -> 8 bf16
    __shared__ uint_t smt[4][16 * 36];      // per-wave t tile, row stride 36 dw
    __shared__ float red[128];              // block partial colsum / colsumsq

    const int w = threadIdx.x >> 6;
    const int lane = threadIdx.x & 63;
    const int q = lane >> 3;
    const int r = lane & 7;
    const int wid = __builtin_amdgcn_readfirstlane((blockIdx.x << 2) | w);
    const bool active = wid < (N_NODES / AGG_CHUNK);
    const int n0 = (active ? wid : 0) * AGG_CHUNK;

    // build W1 bf16 B-fragments: slot (hh,c,L): j -> W1[hh*32+(L>>4)*8+j][c*16+(L&15)]
    for (int s = threadIdx.x; s < 512; s += 256) {
        const int hh = s >> 8, c = (s >> 6) & 3, L = s & 63;
        const int kb = hh * 32 + ((L >> 4) * 8);
        const int out = c * 16 + (L & 15);
        uint_t* dst = (uint_t*)&wfrag[s * 8];
#pragma unroll
        for (int j2 = 0; j2 < 4; j2++) {
            const float lo = W1[(kb + 2 * j2) * 64 + out];
            const float hi = W1[(kb + 2 * j2 + 1) * 64 + out];
            dst[j2] = (uint_t)f2bf(lo) | ((uint_t)f2bf(hi) << 16);
        }
    }
    if (threadIdx.x < 128) red[threadIdx.x] = 0.f;
    __syncthreads();

    // gather 16 nodes (8 pairs), stage t rows as bf16 into smt
    if (active) {
        for (int pp = 0; pp < AGG_CHUNK; pp += 2) {
            const int n = n0 + pp;
            const int sa = rowptr[n],     da = cnt[n];
            const int sb = rowptr[n + 1], db = cnt[n + 1];
            const float idga = invdeg[n], idgb = invdeg[n + 1];
            const int* __restrict__ ca = csr + sa;
            const int* __restrict__ cb = csr + sb;

            float aa[8] = {0,0,0,0,0,0,0,0};
            float ab[8] = {0,0,0,0,0,0,0,0};
            const int mm = min(da, db);
            int e = 0;
            for (; e < mm; e += 8) {
                grp8b(h, ca, e, da, q, r, aa);
                grp8b(h, cb, e, db, q, r, ab);
            }
            for (; e < da; e += 8) grp8b(h, ca, e, da, q, r, aa);
            for (; e < db; e += 8) grp8b(h, cb, e, db, q, r, ab);

#pragma unroll
            for (int j = 0; j < 8; j++) {
                aa[j] += __shfl_xor(aa[j], 8, 64);
                aa[j] += __shfl_xor(aa[j], 16, 64);
                aa[j] += __shfl_xor(aa[j], 32, 64);
                ab[j] += __shfl_xor(ab[j], 8, 64);
                ab[j] += __shfl_xor(ab[j], 16, 64);
                ab[j] += __shfl_xor(ab[j], 32, 64);
            }

            const uint4 sva = *(const uint4*)(h + (size_t)n * 64 + r * 8);
            const uint4 svb = *(const uint4*)(h + (size_t)(n + 1) * 64 + r * 8);
            float sa8[8], sb8[8];
            bf8_to_f32(sva, sa8);
            bf8_to_f32(svb, sb8);
            float ta[8], tb[8];
#pragma unroll
            for (int j = 0; j < 8; j++) {
                ta[j] = fmaf(aa[j], idga, sa8[j]);
                tb[j] = fmaf(ab[j], idgb, sb8[j]);
            }

            if (q < 2) {   // lanes q==0 stage node pp, q==1 stage node pp+1
                const int row = pp + q;
                uint_t* dst = &smt[w][row * 36 + r * 4];
#pragma unroll
                for (int j2 = 0; j2 < 4; j2++) {
                    const float lo = q ? tb[2 * j2]     : ta[2 * j2];
                    const float hi = q ? tb[2 * j2 + 1] : ta[2 * j2 + 1];
                    dst[j2] = (uint_t)f2bf(lo) | ((uint_t)f2bf(hi) << 16);
                }
            }
        }
    }
    __syncthreads();

    // MFMA: A = t tile (m=lane&15, k=quad*8+j), two K-halves
    const int m = lane & 15;
    const int quad = lane >> 4;
    const short8 a0 = *(const short8*)&smt[w][m * 36 + quad * 4];
    const short8 a1 = *(const short8*)&smt[w][m * 36 + 16 + quad * 4];

    float lsum[4], lsq[4];
#pragma unroll
    for (int c = 0; c < 4; c++) {
        const short8 b0 = *(const short8*)&wfrag[(size_t)(c * 64 + lane) * 8];
        const short8 b1f = *(const short8*)&wfrag[(size_t)((4 + c) * 64 + lane) * 8];
        f32x4 D = {0.f, 0.f, 0.f, 0.f};
        D = __builtin_amdgcn_mfma_f32_16x16x32_bf16(a0, b0, D, 0, 0, 0);
        D = __builtin_amdgcn_mfma_f32_16x16x32_bf16(a1, b1f, D, 0, 0, 0);
        const float bv = b1[c * 16 + m];
        float s = 0.f, sq = 0.f;
#pragma unroll
        for (int reg = 0; reg < 4; reg++) {
            const float zv = D[reg] + bv;
            if (active) {
                const int node = n0 + quad * 4 + reg;
                z[(size_t)node * 64 + c * 16 + m] = zv;
            }
            s += zv;
            sq += zv * zv;
        }
        lsum[c] = s;
        lsq[c] = sq;
    }

    if (active) {
#pragma unroll
        for (int c = 0; c < 4; c++) {
            float s = lsum[c], sq = lsq[c];
            s += __shfl_xor(s, 16, 64);
            s += __shfl_xor(s, 32, 64);
            sq += __shfl_xor(sq, 16, 64);
            sq += __shfl_xor(sq, 32, 64);
            if (quad == 0) {
                atomicAdd(&red[c * 16 + m], s);
                atomicAdd(&red[64 + c * 16 + m], sq);
            }
        }
    }
    __syncthreads();
    if (threadIdx.x < 64) {
        atomicAdd(&colsum[threadIdx.x], red[threadIdx.x]);
        atomicAdd(&colsumsq[threadIdx.x], red[64 + threadIdx.x]);
    }
}

// ---------------- BN prep ----------------

__global__ void k_bnprep(float* __restrict__ colsum, float* __restrict__ colsumsq,
                         const float* __restrict__ gamma, const float* __restrict__ beta,
                         float* __restrict__ scale, float* __restrict__ shift) {
    int j = threadIdx.x;  // 64 threads
    float invn = 1.0f / (float)N_NODES;
    float mu = colsum[j] * invn;
    float var = colsumsq[j] * invn - mu * mu;
    float rsg = rsqrtf(var + BN_EPS);
    float sc = gamma[j] * rsg;
    scale[j] = sc;
    shift[j] = beta[j] - mu * sc;
    colsum[j] = 0.f;
    colsumsq[j] = 0.f;
}

// ---------------- Layer pass B: BN + ReLU + GEMV(W2) + pools (r7) ------------

#define CHUNK_M 28  // multiple of 4

__global__ __launch_bounds__(256, 4)
void k_passB(const float* __restrict__ z, const float* __restrict__ W2,
             const float* __restrict__ b2, const float* __restrict__ scale,
             const float* __restrict__ shift, const int* __restrict__ batch,
             ushort_t* __restrict__ hout, float* __restrict__ node_pool,
             float* __restrict__ gacc, int first) {
    const int lane = threadIdx.x & 63;
    int wid_raw = (blockIdx.x << 2) | (threadIdx.x >> 6);
    const int wid = __builtin_amdgcn_readfirstlane(wid_raw);
    const int n0 = wid * CHUNK_M;
    const int n1 = min(N_NODES, n0 + CHUNK_M);

    float w[64];
#pragma unroll
    for (int k = 0; k < 64; k++) w[k] = W2[k * 64 + lane];
#pragma unroll
    for (int k = 0; k < 64; k++) asm("" : "+v"(w[k]));
    const float bj = b2[lane], sc = scale[lane], sh = shift[lane];

    int curg = -1;
    float ga = 0.f;
    for (int n = n0; n + 4 <= n1; n += 4) {
        float ra = fmaxf(fmaf(z[(size_t)n * 64 + lane], sc, sh), 0.f);
        float rb = fmaxf(fmaf(z[(size_t)(n + 1) * 64 + lane], sc, sh), 0.f);
        float rc = fmaxf(fmaf(z[(size_t)(n + 2) * 64 + lane], sc, sh), 0.f);
        float rd = fmaxf(fmaf(z[(size_t)(n + 3) * 64 + lane], sc, sh), 0.f);
        float ha = bj, hb = bj, hc = bj, hd = bj;
#pragma unroll
        for (int k = 0; k < 64; k++) {
            float ka = __int_as_float(__builtin_amdgcn_readlane(__float_as_int(ra), k));
            float kb = __int_as_float(__builtin_amdgcn_readlane(__float_as_int(rb), k));
            float kc = __int_as_float(__builtin_amdgcn_readlane(__float_as_int(rc), k));
            float kd = __int_as_float(__builtin_amdgcn_readlane(__float_as_int(rd), k));
            ha = fmaf(ka, w[k], ha);
            hb = fmaf(kb, w[k], hb);
            hc = fmaf(kc, w[k], hc);
            hd = fmaf(kd, w[k], hd);
        }
        hout[(size_t)n * 64 + lane] = f2bf(ha);
        hout[(size_t)(n + 1) * 64 + lane] = f2bf(hb);
        hout[(size_t)(n + 2) * 64 + lane] = f2bf(hc);
        hout[(size_t)(n + 3) * 64 + lane] = f2bf(hd);
        if (first) {
            node_pool[(size_t)n * 64 + lane] = ha;
            node_pool[(size_t)(n + 1) * 64 + lane] = hb;
            node_pool[(size_t)(n + 2) * 64 + lane] = hc;
            node_pool[(size_t)(n + 3) * 64 + lane] = hd;
        } else {
            node_pool[(size_t)n * 64 + lane] += ha;
            node_pool[(size_t)(n + 1) * 64 + lane] += hb;
            node_pool[(size_t)(n + 2) * 64 + lane] += hc;
            node_pool[(size_t)(n + 3) * 64 + lane] += hd;
        }
        float hv[4] = {ha, hb, hc, hd};
#pragma unroll
        for (int j = 0; j < 4; j++) {
            int g = batch[n + j];
            if (g != curg) {
                if (curg >= 0) atomicAdd(&gacc[curg * 64 + lane], ga);
                ga = 0.f;
                curg = g;
            }
            ga += hv[j];
        }
    }
    if (curg >= 0) atomicAdd(&gacc[curg * 64 + lane], ga);
}

__global__ void k_gfinal(const float* __restrict__ gacc, const float* __restrict__ invg,
                         float* __restrict__ gout) {
    int i = blockIdx.x * blockDim.x + threadIdx.x;
    if (i < NGRAPH * 64) gout[i] = gacc[i] * invg[i >> 6];
}

// ---------------- launch ----------------

extern "C" void kernel_launch(void* const* d_in, const int* in_sizes, int n_in,
                              void* d_out, int out_size, void* d_ws, size_t ws_size,
                              hipStream_t stream) {
    (void)in_sizes; (void)n_in; (void)out_size; (void)ws_size;
    const float* x     = (const float*)d_in[0];
    const int*   ei    = (const int*)d_in[1];
    const int*   batch = (const int*)d_in[2];
    const float* W1    = (const float*)d_in[3];
    const float* b1    = (const float*)d_in[4];
    const float* gamma = (const float*)d_in[5];
    const float* beta  = (const float*)d_in[6];
    const float* W2    = (const float*)d_in[7];
    const float* b2    = (const float*)d_in[8];
    float* out = (float*)d_out;  // [N*64] node_pool, then [G*64] g_pool

    // element offsets (4B units)
    size_t o = 0;
    size_t o_cntS    = o; o += (size_t)NSHARD * N_NODES;
    size_t o_colsum  = o; o += 64;
    size_t o_colsq   = o; o += 64;
    size_t o_gacc    = o; o += (size_t)NGRAPH * 64;
    size_t zero_elems = o;
    size_t o_cnt     = o; o += N_NODES;
    size_t o_rowptr  = o; o += N_NODES;
    size_t o_bsums   = o; o += 512;
    size_t o_boffs   = o; o += 512;
    size_t o_invdeg  = o; o += N_NODES;
    size_t o_invg    = o; o += NGRAPH;
    size_t o_scale   = o; o += 64;
    size_t o_shift   = o; o += 64;
    size_t o_rank    = o; o += N_EDGES;
    size_t o_csr     = o; o += N_EDGES;
    size_t o_bufA    = o; o += (size_t)N_NODES * 64;   // z, fp32
    size_t o_bufB    = o; o += (size_t)N_NODES * 16;   // h,  bf16 (N*64 ushorts)
    size_t o_xh      = o; o += (size_t)N_NODES * 16;   // x,  bf16

    int*   wsi = (int*)d_ws;
    float* wsf = (float*)d_ws;
    int*      cntS   = wsi + o_cntS;
    float*    colsum = wsf + o_colsum;
    float*    colsq  = wsf + o_colsq;
    float*    gacc   = wsf + o_gacc;
    int*      cnt    = wsi + o_cnt;
    int*      rowptr = wsi + o_rowptr;
    int*      bsums  = wsi + o_bsums;
    int*      boffs  = wsi + o_boffs;
    float*    invdeg = wsf + o_invdeg;
    float*    invg   = wsf + o_invg;
    float*    scale  = wsf + o_scale;
    float*    shift  = wsf + o_shift;
    int*      rank   = wsi + o_rank;
    int*      csr    = wsi + o_csr;
    float*    bufA   = wsf + o_bufA;
    ushort_t* bufB   = (ushort_t*)(wsi + o_bufB);
    ushort_t* xh     = (ushort_t*)(wsi + o_xh);

    hipMemsetAsync(d_ws, 0, zero_elems * 4, stream);

    const int eb = (N_EDGES + 255) / 256;
    const int nb = (N_NODES + 255) / 256;  // 391 <= 512

    k_hist<<<eb, 256, 0, stream>>>(ei, cntS, rank);
    k_xcast<<<(N_NODES * 16 + 255) / 256, 256, 0, stream>>>(x, xh);
    k_sumsh<<<nb, 256, 0, stream>>>(cntS, cnt);
    k_scan1<<<nb, 256, 0, stream>>>(cnt, rowptr, bsums);
    k_scan2<<<1, 512, 0, stream>>>(bsums, boffs, nb);
    k_scan3<<<nb, 256, 0, stream>>>(rowptr, boffs);
    k_prep<<<nb, 256, 0, stream>>>(cnt, batch, invdeg, invg);
    k_fill<<<eb, 256, 0, stream>>>(ei, rowptr, cntS, rank, csr);

    const int gridA = (N_NODES / AGG_CHUNK + 3) / 4;                  // 1563
    const int gridM = (N_NODES + CHUNK_M * 4 - 1) / (CHUNK_M * 4);    // 893
    for (int l = 0; l < NLAYER; l++) {
        const ushort_t* h_in = (l == 0) ? xh : bufB;
        k_passA<<<gridA, 256, 0, stream>>>(h_in, W1 + l * 4096, b1 + l * 64,
                                           rowptr, cnt, csr, invdeg,
                                           bufA, colsum, colsq);
        k_bnprep<<<1, 64, 0, stream>>>(colsum, colsq, gamma + l * 64, beta + l * 64,
                                       scale, shift);
        k_passB<<<gridM, 256, 0, stream>>>(bufA, W2 + l * 4096, b2 + l * 64,
                                           scale, shift, batch,
                                           bufB, out, gacc, (l == 0) ? 1 : 0);
    }
    k_gfinal<<<32, 256, 0, stream>>>(gacc, invg, out + (size_t)N_NODES * 64);
}